// Round 2
// baseline (534.893 us; speedup 1.0000x reference)
//
#include <hip/hip_runtime.h>

// Problem: B=4, S=2048, D=1024, H=16, HD=64.
#define NB 4
#define NS 2048
#define ND 1024
#define NH 16
#define NE 64
#define NM (NB*NS)   // 8192 rows

typedef __attribute__((ext_vector_type(8))) __bf16 bf16x8;           // MFMA A/B frag (4 VGPRs)
typedef __attribute__((ext_vector_type(8))) unsigned short us8;      // 16B staging vector
typedef __attribute__((ext_vector_type(4))) float f32x4;             // MFMA C/D frag

__device__ __forceinline__ float bf2f(unsigned short h) {
  union { unsigned u; float f; } c; c.u = ((unsigned)h) << 16; return c.f;
}
__device__ __forceinline__ unsigned short f2bf(float f) {
  union { float f; unsigned u; } c; c.f = f;
  return (unsigned short)((c.u + 0x7fffu + ((c.u >> 16) & 1u)) >> 16);
}
__device__ __forceinline__ void load16_to_lds(const void* g, void* l) {
  __builtin_amdgcn_global_load_lds(
      (__attribute__((address_space(1))) void*)(void*)(unsigned long long)(const char*)g,
      (__attribute__((address_space(3))) void*)l, 16, 0, 0);
}

// ---------- dtype detection: is d_in data bf16 (1) or fp32 (0)? ----------
// Sample low u16 of 256 u32 words of x. bf16 pairs: low u16 is a bf16 of
// ~N(0,1) -> exp field in [100,142] essentially always. fp32: low u16 is
// mantissa bits -> exp field uniform -> ~17% hits.
__global__ void detect_dtype(const unsigned* __restrict__ x, int* __restrict__ flag) {
  __shared__ int cnt;
  if (threadIdx.x == 0) cnt = 0;
  __syncthreads();
  unsigned w = x[((unsigned)threadIdx.x * 16381u) & ((1u << 21) - 1u)];
  unsigned lo = w & 0xFFFFu;
  int e = (int)((lo >> 7) & 0xFF);
  int plausible = (lo == 0u) || (e >= 100 && e <= 142);
  atomicAdd(&cnt, plausible);
  __syncthreads();
  if (threadIdx.x == 0) *flag = (cnt >= 192) ? 1 : 0;
}

// ---------- canonicalize any input to bf16 ----------
__global__ void conv_to_bf16(const void* __restrict__ src, unsigned short* __restrict__ dst,
                             int n, const int* __restrict__ flag) {
  int stride = gridDim.x * blockDim.x;
  int i0 = blockIdx.x * blockDim.x + threadIdx.x;
  if (*flag) {
    const unsigned short* s = (const unsigned short*)src;
    for (int i = i0; i < n; i += stride) dst[i] = s[i];
  } else {
    const float* s = (const float*)src;
    for (int i = i0; i < n; i += stride) dst[i] = f2bf(s[i]);
  }
}

// ---------- transpose: in[K][N] -> out[N][K] (bf16) ----------
__global__ __launch_bounds__(256) void transpose_k(const unsigned short* __restrict__ in,
                                                   unsigned short* __restrict__ out,
                                                   int K, int N) {
  __shared__ unsigned short tile[32][33];
  int n0 = blockIdx.x * 32, k0 = blockIdx.y * 32;
  int tx = threadIdx.x, ty = threadIdx.y;   // (32,8)
#pragma unroll
  for (int i = 0; i < 4; ++i)
    tile[ty + 8*i][tx] = in[(size_t)(k0 + ty + 8*i) * N + n0 + tx];
  __syncthreads();
#pragma unroll
  for (int i = 0; i < 4; ++i)
    out[(size_t)(n0 + ty + 8*i) * K + k0 + tx] = tile[tx][ty + 8*i];
}

// ---------- m97-style GEMM core: C[128x128] = A[M,K] * Bt[N,K]^T ----------
__device__ __forceinline__ void gemm_core(const unsigned short* __restrict__ A,
                                          const unsigned short* __restrict__ Bt,
                                          int K, int m0, int n0,
                                          unsigned short* As, unsigned short* Bs,
                                          f32x4 (&acc)[4][4]) {
  int t = threadIdx.x;
  int lane = t & 63;
  int w = t >> 6, wr = w >> 1, wc = w & 1;
  int frm = lane & 15, fko = (lane >> 4) * 8;
  for (int kk = 0; kk < K; kk += 32) {
#pragma unroll
    for (int c = 0; c < 2; ++c) {
      int L = c * 256 + t;
      int r = L >> 2, ko = (L & 3) * 8;
      load16_to_lds(A  + (size_t)(m0 + r) * K + kk + ko, (char*)As + L * 16);
      load16_to_lds(Bt + (size_t)(n0 + r) * K + kk + ko, (char*)Bs + L * 16);
    }
    __syncthreads();
    bf16x8 a[4], b[4];
#pragma unroll
    for (int i = 0; i < 4; ++i) a[i] = *(const bf16x8*)(As + (64*wr + 16*i + frm) * 32 + fko);
#pragma unroll
    for (int j = 0; j < 4; ++j) b[j] = *(const bf16x8*)(Bs + (64*wc + 16*j + frm) * 32 + fko);
#pragma unroll
    for (int i = 0; i < 4; ++i)
#pragma unroll
      for (int j = 0; j < 4; ++j)
        acc[i][j] = __builtin_amdgcn_mfma_f32_16x16x32_bf16(a[i], b[j], acc[i][j], 0, 0, 0);
    __syncthreads();
  }
}

// ---------- QKV projection, scatter to (B,H,S,HD), q scaled by 1/8 ----------
__global__ __launch_bounds__(256) void gemm_qkv(const unsigned short* __restrict__ X,
                                                const unsigned short* __restrict__ W1T,
                                                const unsigned short* __restrict__ battn,
                                                unsigned short* __restrict__ qb,
                                                unsigned short* __restrict__ kb,
                                                unsigned short* __restrict__ vb) {
  __shared__ unsigned short As[128 * 32];
  __shared__ unsigned short Bs[128 * 32];
  int m0 = blockIdx.y * 128, n0 = blockIdx.x * 128;
  f32x4 acc[4][4] = {};
  gemm_core(X, W1T, ND, m0, n0, As, Bs, acc);
  int t = threadIdx.x, lane = t & 63, w = t >> 6, wr = w >> 1, wc = w & 1;
  int coln = lane & 15, rbase = (lane >> 4) * 4;
#pragma unroll
  for (int j = 0; j < 4; ++j) {
    int nn = n0 + 64*wc + 16*j + coln;       // 0..3071
    int qq = nn >> 10;                       // 0=q 1=k 2=v
    int h  = (nn >> 6) & 15;
    int e  = nn & 63;
    float bias = bf2f(battn[nn]);
    unsigned short* dst = (qq == 0) ? qb : ((qq == 1) ? kb : vb);
    float scale = (qq == 0) ? 0.125f : 1.0f;
#pragma unroll
    for (int i = 0; i < 4; ++i) {
#pragma unroll
      for (int rr = 0; rr < 4; ++rr) {
        int mm = m0 + 64*wr + 16*i + rbase + rr;
        int bb = mm >> 11, s = mm & 2047;
        float v = (acc[i][j][rr] + bias) * scale;
        dst[(((size_t)bb * NH + h) * NS + s) * NE + e] = f2bf(v);
      }
    }
  }
}

// ---------- causal flash attention, 64-row q-tiles, 4 waves/block ----------
__global__ __launch_bounds__(256) void attn_causal(const unsigned short* __restrict__ qb,
                                                   const unsigned short* __restrict__ kb,
                                                   const unsigned short* __restrict__ vb,
                                                   unsigned short* __restrict__ ob) {
  __shared__ unsigned short Qs[64 * 72];
  __shared__ unsigned short Ks[64 * 72];
  __shared__ unsigned short Vt[64 * 72];
  __shared__ unsigned short Ps[64 * 72];

  int qt = blockIdx.x, bh = blockIdx.y;
  int q0 = qt * 64;
  size_t base = (size_t)bh * NS * NE;
  int t = threadIdx.x, lane = t & 63, w = t >> 6;
  int qd = lane >> 4, li = lane & 15;

  for (int ch = t; ch < 512; ch += 256) {
    int r = ch >> 3, c = ch & 7;
    *(us8*)(Qs + r * 72 + c * 8) = *(const us8*)(qb + base + (size_t)(q0 + r) * NE + c * 8);
  }
  __syncthreads();
  bf16x8 qa0 = *(const bf16x8*)(Qs + (16*w + li) * 72 + qd * 8);
  bf16x8 qa1 = *(const bf16x8*)(Qs + (16*w + li) * 72 + 32 + qd * 8);

  f32x4 o[4] = {};
  float m_run[4], l_run[4];
#pragma unroll
  for (int rr = 0; rr < 4; ++rr) { m_run[rr] = -1e5f; l_run[rr] = 0.f; }

  for (int kt = 0; kt <= qt; ++kt) {
    int k0 = kt * 64;
    for (int ch = t; ch < 512; ch += 256) {
      int r = ch >> 3, c = ch & 7;
      *(us8*)(Ks + r * 72 + c * 8) = *(const us8*)(kb + base + (size_t)(k0 + r) * NE + c * 8);
      us8 vv = *(const us8*)(vb + base + (size_t)(k0 + r) * NE + c * 8);
#pragma unroll
      for (int jj = 0; jj < 8; ++jj) Vt[(c * 8 + jj) * 72 + r] = vv[jj];
    }
    __syncthreads();

    f32x4 sfr[4];
#pragma unroll
    for (int c = 0; c < 4; ++c) {
      bf16x8 kf0 = *(const bf16x8*)(Ks + (16*c + li) * 72 + qd * 8);
      bf16x8 kf1 = *(const bf16x8*)(Ks + (16*c + li) * 72 + 32 + qd * 8);
      f32x4 s = {};
      s = __builtin_amdgcn_mfma_f32_16x16x32_bf16(qa0, kf0, s, 0, 0, 0);
      s = __builtin_amdgcn_mfma_f32_16x16x32_bf16(qa1, kf1, s, 0, 0, 0);
      int colk = k0 + 16*c + li;
#pragma unroll
      for (int rr = 0; rr < 4; ++rr) {
        int rowq = q0 + 16*w + qd * 4 + rr;
        // clamp kills any inf/NaN (fmaxf/fminf return the non-NaN operand)
        float sv = fminf(fmaxf(s[rr], -1e4f), 1e4f);
        sfr[c][rr] = (colk <= rowq) ? sv : -1e5f;
      }
    }
    f32x4 rmax = sfr[0];
#pragma unroll
    for (int c = 1; c < 4; ++c)
#pragma unroll
      for (int rr = 0; rr < 4; ++rr) rmax[rr] = fmaxf(rmax[rr], sfr[c][rr]);
#pragma unroll
    for (int off = 1; off < 16; off <<= 1)
#pragma unroll
      for (int rr = 0; rr < 4; ++rr) rmax[rr] = fmaxf(rmax[rr], __shfl_xor(rmax[rr], off, 64));

    float al[4];
#pragma unroll
    for (int rr = 0; rr < 4; ++rr) {
      float mn = fmaxf(m_run[rr], rmax[rr]);
      al[rr] = __expf(m_run[rr] - mn);
      m_run[rr] = mn;
    }
    f32x4 rsum = {};
#pragma unroll
    for (int c = 0; c < 4; ++c)
#pragma unroll
      for (int rr = 0; rr < 4; ++rr) {
        float pv = __expf(sfr[c][rr] - m_run[rr]);
        rsum[rr] += pv;
        Ps[(16*w + qd * 4 + rr) * 72 + 16*c + li] = f2bf(pv);
      }
#pragma unroll
    for (int off = 1; off < 16; off <<= 1)
#pragma unroll
      for (int rr = 0; rr < 4; ++rr) rsum[rr] += __shfl_xor(rsum[rr], off, 64);
#pragma unroll
    for (int rr = 0; rr < 4; ++rr) l_run[rr] = al[rr] * l_run[rr] + rsum[rr];
#pragma unroll
    for (int c = 0; c < 4; ++c)
#pragma unroll
      for (int rr = 0; rr < 4; ++rr) o[c][rr] *= al[rr];

    bf16x8 pa0 = *(const bf16x8*)(Ps + (16*w + li) * 72 + qd * 8);
    bf16x8 pa1 = *(const bf16x8*)(Ps + (16*w + li) * 72 + 32 + qd * 8);
#pragma unroll
    for (int c = 0; c < 4; ++c) {
      bf16x8 vf0 = *(const bf16x8*)(Vt + (16*c + li) * 72 + qd * 8);
      bf16x8 vf1 = *(const bf16x8*)(Vt + (16*c + li) * 72 + 32 + qd * 8);
      o[c] = __builtin_amdgcn_mfma_f32_16x16x32_bf16(pa0, vf0, o[c], 0, 0, 0);
      o[c] = __builtin_amdgcn_mfma_f32_16x16x32_bf16(pa1, vf1, o[c], 0, 0, 0);
    }
    __syncthreads();
  }

  int bb = bh >> 4, hh = bh & 15;
#pragma unroll
  for (int c = 0; c < 4; ++c) {
#pragma unroll
    for (int rr = 0; rr < 4; ++rr) {
      int rowm = 16*w + qd * 4 + rr;
      float inv = 1.0f / fmaxf(l_run[rr], 1e-30f);
      float ov = o[c][rr] * inv;
      int e = 16*c + li;
      ob[(((size_t)bb * NS + (q0 + rowm)) * NH + hh) * NE + e] = f2bf(ov);
    }
  }
}

// ---------- output projection; store dtype per flag ----------
__global__ __launch_bounds__(256) void gemm_proj(const unsigned short* __restrict__ A,
                                                 const unsigned short* __restrict__ W2T,
                                                 const unsigned short* __restrict__ bproj,
                                                 void* __restrict__ outv,
                                                 const int* __restrict__ flag) {
  __shared__ unsigned short As[128 * 32];
  __shared__ unsigned short Bs[128 * 32];
  int m0 = blockIdx.y * 128, n0 = blockIdx.x * 128;
  f32x4 acc[4][4] = {};
  gemm_core(A, W2T, ND, m0, n0, As, Bs, acc);
  int isbf = *flag;
  unsigned short* out16 = (unsigned short*)outv;
  float* out32 = (float*)outv;
  int t = threadIdx.x, lane = t & 63, w = t >> 6, wr = w >> 1, wc = w & 1;
  int coln = lane & 15, rbase = (lane >> 4) * 4;
#pragma unroll
  for (int j = 0; j < 4; ++j) {
    int nn = n0 + 64*wc + 16*j + coln;
    float bias = bf2f(bproj[nn]);
#pragma unroll
    for (int i = 0; i < 4; ++i) {
#pragma unroll
      for (int rr = 0; rr < 4; ++rr) {
        int mm = m0 + 64*wr + 16*i + rbase + rr;
        float v = acc[i][j][rr] + bias;
        if (isbf) out16[(size_t)mm * ND + nn] = f2bf(v);
        else      out32[(size_t)mm * ND + nn] = v;
      }
    }
  }
}

extern "C" void kernel_launch(void* const* d_in, const int* in_sizes, int n_in,
                              void* d_out, int out_size, void* d_ws, size_t ws_size,
                              hipStream_t stream) {
  (void)in_sizes; (void)n_in; (void)out_size; (void)ws_size;
  char* ws = (char*)d_ws;
  // layout (bytes); lifetimes are sequential so converted inputs overlay later buffers
  unsigned short* W1T = (unsigned short*)(ws);                       // 6,291,456
  unsigned short* W2T = (unsigned short*)(ws + 6291456);             // 2,097,152
  unsigned short* qb  = (unsigned short*)(ws + 8388608);             // 16 MB
  unsigned short* kb  = (unsigned short*)(ws + 25165824);            // 16 MB
  unsigned short* vb  = (unsigned short*)(ws + 41943040);            // 16 MB
  unsigned short* ob  = (unsigned short*)(ws + 58720256);            // 16 MB
  unsigned short* bac = (unsigned short*)(ws + 75497472);            // 8 KB
  unsigned short* bpc = (unsigned short*)(ws + 75505664);            // 8 KB
  int*            flg = (int*)(ws + 75513856);
  unsigned short* wac = qb;   // converted w_attn, dead before qb written
  unsigned short* wpc = kb;   // converted w_proj, dead before kb written
  unsigned short* xc  = ob;   // converted x, dead before ob written

  detect_dtype<<<1, 256, 0, stream>>>((const unsigned*)d_in[0], flg);
  conv_to_bf16<<<2048, 256, 0, stream>>>(d_in[0], xc,  NB*NS*ND, flg);   // 8,388,608
  conv_to_bf16<<<1024, 256, 0, stream>>>(d_in[1], wac, ND*3*NH*NE, flg); // 3,145,728
  conv_to_bf16<<<512,  256, 0, stream>>>(d_in[3], wpc, NH*NE*ND, flg);   // 1,048,576
  conv_to_bf16<<<12,   256, 0, stream>>>(d_in[2], bac, 3*NH*NE, flg);    // 3,072
  conv_to_bf16<<<4,    256, 0, stream>>>(d_in[4], bpc, ND, flg);         // 1,024

  transpose_k<<<dim3(3072/32, 1024/32), dim3(32, 8), 0, stream>>>(wac, W1T, 1024, 3072);
  transpose_k<<<dim3(1024/32, 1024/32), dim3(32, 8), 0, stream>>>(wpc, W2T, 1024, 1024);
  gemm_qkv<<<dim3(3072/128, NM/128), 256, 0, stream>>>(xc, W1T, bac, qb, kb, vb);
  attn_causal<<<dim3(NS/64, NB*NH), 256, 0, stream>>>(qb, kb, vb, ob);
  gemm_proj<<<dim3(1024/128, NM/128), 256, 0, stream>>>(ob, W2T, bpc, d_out, flg);
}

// Round 3
// 467.909 us; speedup vs baseline: 1.1432x; 1.1432x over previous
//
#include <hip/hip_runtime.h>

// Problem: B=4, S=2048, D=1024, H=16, HD=64.
#define NB 4
#define NS 2048
#define ND 1024
#define NH 16
#define NE 64
#define NM (NB*NS)   // 8192 rows

typedef __attribute__((ext_vector_type(8))) __bf16 bf16x8;           // MFMA A/B frag (4 VGPRs)
typedef __attribute__((ext_vector_type(8))) unsigned short us8;      // 16B staging vector
typedef __attribute__((ext_vector_type(4))) float f32x4;             // MFMA C/D frag

__device__ __forceinline__ float bf2f(unsigned short h) {
  union { unsigned u; float f; } c; c.u = ((unsigned)h) << 16; return c.f;
}
__device__ __forceinline__ unsigned short f2bf(float f) {
  union { float f; unsigned u; } c; c.f = f;
  return (unsigned short)((c.u + 0x7fffu + ((c.u >> 16) & 1u)) >> 16);
}
__device__ __forceinline__ void load16_to_lds(const void* g, void* l) {
  __builtin_amdgcn_global_load_lds(
      (__attribute__((address_space(1))) void*)(void*)(unsigned long long)(const char*)g,
      (__attribute__((address_space(3))) void*)l, 16, 0, 0);
}

// ---------- dtype detection: is d_in data bf16 (1) or fp32 (0)? ----------
__global__ void detect_dtype(const unsigned* __restrict__ x, int* __restrict__ flag) {
  __shared__ int cnt;
  if (threadIdx.x == 0) cnt = 0;
  __syncthreads();
  unsigned w = x[((unsigned)threadIdx.x * 16381u) & ((1u << 21) - 1u)];
  unsigned lo = w & 0xFFFFu;
  int e = (int)((lo >> 7) & 0xFF);
  int plausible = (lo == 0u) || (e >= 100 && e <= 142);
  atomicAdd(&cnt, plausible);
  __syncthreads();
  if (threadIdx.x == 0) *flag = (cnt >= 192) ? 1 : 0;
}

// ---------- canonicalize any input to bf16 ----------
__global__ void conv_to_bf16(const void* __restrict__ src, unsigned short* __restrict__ dst,
                             int n, const int* __restrict__ flag) {
  int stride = gridDim.x * blockDim.x;
  int i0 = blockIdx.x * blockDim.x + threadIdx.x;
  if (*flag) {
    const unsigned short* s = (const unsigned short*)src;
    for (int i = i0; i < n; i += stride) dst[i] = s[i];
  } else {
    const float* s = (const float*)src;
    for (int i = i0; i < n; i += stride) dst[i] = f2bf(s[i]);
  }
}

// ---------- transpose: in[K][N] -> out[N][K] (bf16) ----------
__global__ __launch_bounds__(256) void transpose_k(const unsigned short* __restrict__ in,
                                                   unsigned short* __restrict__ out,
                                                   int K, int N) {
  __shared__ unsigned short tile[32][33];
  int n0 = blockIdx.x * 32, k0 = blockIdx.y * 32;
  int tx = threadIdx.x, ty = threadIdx.y;   // (32,8)
#pragma unroll
  for (int i = 0; i < 4; ++i)
    tile[ty + 8*i][tx] = in[(size_t)(k0 + ty + 8*i) * N + n0 + tx];
  __syncthreads();
#pragma unroll
  for (int i = 0; i < 4; ++i)
    out[(size_t)(n0 + ty + 8*i) * K + k0 + tx] = tile[tx][ty + 8*i];
}

// ---------- m97-style GEMM core: C[128x128] = A[M,K] * Bt[N,K]^T ----------
__device__ __forceinline__ void gemm_core(const unsigned short* __restrict__ A,
                                          const unsigned short* __restrict__ Bt,
                                          int K, int m0, int n0,
                                          unsigned short* As, unsigned short* Bs,
                                          f32x4 (&acc)[4][4]) {
  int t = threadIdx.x;
  int lane = t & 63;
  int w = t >> 6, wr = w >> 1, wc = w & 1;
  int frm = lane & 15, fko = (lane >> 4) * 8;
  for (int kk = 0; kk < K; kk += 32) {
#pragma unroll
    for (int c = 0; c < 2; ++c) {
      int L = c * 256 + t;
      int r = L >> 2, ko = (L & 3) * 8;
      load16_to_lds(A  + (size_t)(m0 + r) * K + kk + ko, (char*)As + L * 16);
      load16_to_lds(Bt + (size_t)(n0 + r) * K + kk + ko, (char*)Bs + L * 16);
    }
    __syncthreads();
    bf16x8 a[4], b[4];
#pragma unroll
    for (int i = 0; i < 4; ++i) a[i] = *(const bf16x8*)(As + (64*wr + 16*i + frm) * 32 + fko);
#pragma unroll
    for (int j = 0; j < 4; ++j) b[j] = *(const bf16x8*)(Bs + (64*wc + 16*j + frm) * 32 + fko);
#pragma unroll
    for (int i = 0; i < 4; ++i)
#pragma unroll
      for (int j = 0; j < 4; ++j)
        acc[i][j] = __builtin_amdgcn_mfma_f32_16x16x32_bf16(a[i], b[j], acc[i][j], 0, 0, 0);
    __syncthreads();
  }
}

// ---------- QKV projection, scatter q/k:(B,H,S,E), v:(B,H,E,S); q scaled 1/8 ----------
__global__ __launch_bounds__(256) void gemm_qkv(const unsigned short* __restrict__ X,
                                                const unsigned short* __restrict__ W1T,
                                                const unsigned short* __restrict__ battn,
                                                unsigned short* __restrict__ qb,
                                                unsigned short* __restrict__ kb,
                                                unsigned short* __restrict__ vb) {
  __shared__ unsigned short As[128 * 32];
  __shared__ unsigned short Bs[128 * 32];
  int m0 = blockIdx.y * 128, n0 = blockIdx.x * 128;
  f32x4 acc[4][4] = {};
  gemm_core(X, W1T, ND, m0, n0, As, Bs, acc);
  int t = threadIdx.x, lane = t & 63, w = t >> 6, wr = w >> 1, wc = w & 1;
  int coln = lane & 15, rbase = (lane >> 4) * 4;
#pragma unroll
  for (int j = 0; j < 4; ++j) {
    int nn = n0 + 64*wc + 16*j + coln;       // 0..3071
    int qq = nn >> 10;                       // 0=q 1=k 2=v
    int h  = (nn >> 6) & 15;
    int e  = nn & 63;
    float bias = bf2f(battn[nn]);
    unsigned short* dst = (qq == 0) ? qb : ((qq == 1) ? kb : vb);
    float scale = (qq == 0) ? 0.125f : 1.0f;
#pragma unroll
    for (int i = 0; i < 4; ++i) {
#pragma unroll
      for (int rr = 0; rr < 4; ++rr) {
        int mm = m0 + 64*wr + 16*i + rbase + rr;
        int bb = mm >> 11, s = mm & 2047;
        float v = (acc[i][j][rr] + bias) * scale;
        size_t idx;
        if (qq == 2) idx = (((size_t)bb * NH + h) * NE + e) * NS + s;   // V transposed
        else         idx = (((size_t)bb * NH + h) * NS + s) * NE + e;
        dst[idx] = f2bf(v);
      }
    }
  }
}

// ---------- causal flash attention, 128-row q-tiles, 4 waves/block ----------
// wave w owns q-rows [32w, 32w+32) = 2 m-frags. K: (B,H,S,E). V: (B,H,E,S) pre-transposed.
__global__ __launch_bounds__(256, 4) void attn_causal(const unsigned short* __restrict__ qb,
                                                      const unsigned short* __restrict__ kb,
                                                      const unsigned short* __restrict__ vtb,
                                                      unsigned short* __restrict__ ob) {
  __shared__ unsigned short QPs[128 * 72];  // Q staging, then P (A-operand layout), pitch 72
  __shared__ unsigned short Ks[64 * 64];    // [key][e], pitch 64 (global_load_lds)
  __shared__ unsigned short Vt[64 * 64];    // [e][key], pitch 64 (global_load_lds)

  int qt = (int)gridDim.x - 1 - (int)blockIdx.x;  // long blocks dispatch first
  int bh = blockIdx.y;
  int q0 = qt * 128;
  size_t base = (size_t)bh * NS * NE;
  int t = threadIdx.x, lane = t & 63, w = t >> 6;
  int qd = lane >> 4, li = lane & 15;

  // stage Q (128x64) into QPs (pitch 72)
  for (int ch = t; ch < 1024; ch += 256) {
    int r = ch >> 3, c8 = ch & 7;
    *(us8*)(QPs + r * 72 + c8 * 8) = *(const us8*)(qb + base + (size_t)(q0 + r) * NE + c8 * 8);
  }
  __syncthreads();
  bf16x8 qa[2][2];
#pragma unroll
  for (int i = 0; i < 2; ++i)
#pragma unroll
    for (int k2 = 0; k2 < 2; ++k2)
      qa[i][k2] = *(const bf16x8*)(QPs + (32*w + 16*i + li) * 72 + k2 * 32 + qd * 8);
  __syncthreads();  // everyone done reading Q before Ps overwrites it

  f32x4 o[2][4] = {};
  float m_run[2][4], l_run[2][4];
#pragma unroll
  for (int i = 0; i < 2; ++i)
#pragma unroll
    for (int rr = 0; rr < 4; ++rr) { m_run[i][rr] = -1e5f; l_run[i][rr] = 0.f; }

  int ktmax = 2 * qt + 1;
  for (int kt = 0; kt <= ktmax; ++kt) {
    int k0 = kt * 64;
    // stage K tile [key][e] and V^T tile [e][key] via async DMA
#pragma unroll
    for (int c = 0; c < 2; ++c) {
      int ch = c * 256 + t;
      int r = ch >> 3, s8 = (ch & 7) * 8;
      load16_to_lds(kb  + base + (size_t)(k0 + r) * NE + s8, (char*)Ks + ch * 16);
      load16_to_lds(vtb + base + (size_t)r * NS + k0 + s8,   (char*)Vt + ch * 16);
    }
    __syncthreads();

    int need_mask = (kt >= 2 * qt);
#pragma unroll
    for (int i = 0; i < 2; ++i) {
      f32x4 sfr[4];
#pragma unroll
      for (int c = 0; c < 4; ++c) {
        bf16x8 kf0 = *(const bf16x8*)(Ks + (16*c + li) * 64 + qd * 8);
        bf16x8 kf1 = *(const bf16x8*)(Ks + (16*c + li) * 64 + 32 + qd * 8);
        f32x4 s = {};
        s = __builtin_amdgcn_mfma_f32_16x16x32_bf16(qa[i][0], kf0, s, 0, 0, 0);
        s = __builtin_amdgcn_mfma_f32_16x16x32_bf16(qa[i][1], kf1, s, 0, 0, 0);
        sfr[c] = s;
      }
      if (need_mask) {
#pragma unroll
        for (int c = 0; c < 4; ++c) {
          int colk = k0 + 16*c + li;
#pragma unroll
          for (int rr = 0; rr < 4; ++rr) {
            int rowq = q0 + 32*w + 16*i + qd*4 + rr;
            if (colk > rowq) sfr[c][rr] = -1e9f;
          }
        }
      }
      // row max over 64 keys
      f32x4 rmax = sfr[0];
#pragma unroll
      for (int c = 1; c < 4; ++c)
#pragma unroll
        for (int rr = 0; rr < 4; ++rr) rmax[rr] = fmaxf(rmax[rr], sfr[c][rr]);
#pragma unroll
      for (int off = 1; off < 16; off <<= 1)
#pragma unroll
        for (int rr = 0; rr < 4; ++rr) rmax[rr] = fmaxf(rmax[rr], __shfl_xor(rmax[rr], off, 64));

      float al[4];
#pragma unroll
      for (int rr = 0; rr < 4; ++rr) {
        float mn = fmaxf(m_run[i][rr], rmax[rr]);
        al[rr] = __expf(m_run[i][rr] - mn);
        m_run[i][rr] = mn;
      }
      f32x4 rsum = {};
#pragma unroll
      for (int c = 0; c < 4; ++c)
#pragma unroll
        for (int rr = 0; rr < 4; ++rr) {
          float pv = __expf(sfr[c][rr] - m_run[i][rr]);
          rsum[rr] += pv;
          QPs[(32*w + 16*i + qd*4 + rr) * 72 + 16*c + li] = f2bf(pv);
        }
#pragma unroll
      for (int off = 1; off < 16; off <<= 1)
#pragma unroll
        for (int rr = 0; rr < 4; ++rr) rsum[rr] += __shfl_xor(rsum[rr], off, 64);
#pragma unroll
      for (int rr = 0; rr < 4; ++rr) l_run[i][rr] = al[rr] * l_run[i][rr] + rsum[rr];
#pragma unroll
      for (int c = 0; c < 4; ++c)
#pragma unroll
        for (int rr = 0; rr < 4; ++rr) o[i][c][rr] *= al[rr];
    }

    // O += P V : P rows are wave-local in QPs (no barrier needed write->read)
    bf16x8 pa[2][2];
#pragma unroll
    for (int i = 0; i < 2; ++i)
#pragma unroll
      for (int k2 = 0; k2 < 2; ++k2)
        pa[i][k2] = *(const bf16x8*)(QPs + (32*w + 16*i + li) * 72 + k2 * 32 + qd * 8);
#pragma unroll
    for (int c = 0; c < 4; ++c) {
      bf16x8 vf0 = *(const bf16x8*)(Vt + (16*c + li) * 64 + qd * 8);
      bf16x8 vf1 = *(const bf16x8*)(Vt + (16*c + li) * 64 + 32 + qd * 8);
#pragma unroll
      for (int i = 0; i < 2; ++i) {
        o[i][c] = __builtin_amdgcn_mfma_f32_16x16x32_bf16(pa[i][0], vf0, o[i][c], 0, 0, 0);
        o[i][c] = __builtin_amdgcn_mfma_f32_16x16x32_bf16(pa[i][1], vf1, o[i][c], 0, 0, 0);
      }
    }
    __syncthreads();  // protect Ks/Vt (and QPs vs next Q-frag... P rewrite) for next iter
  }

  // write O to (B,S,H,E)
  int bb = bh >> 4, hh = bh & 15;
#pragma unroll
  for (int i = 0; i < 2; ++i)
#pragma unroll
    for (int c = 0; c < 4; ++c)
#pragma unroll
      for (int rr = 0; rr < 4; ++rr) {
        int rowm = 32*w + 16*i + qd*4 + rr;
        float inv = 1.0f / fmaxf(l_run[i][rr], 1e-30f);
        float ov = o[i][c][rr] * inv;
        int e = 16*c + li;
        ob[(((size_t)bb * NS + (q0 + rowm)) * NH + hh) * NE + e] = f2bf(ov);
      }
}

// ---------- output projection; store dtype per flag ----------
__global__ __launch_bounds__(256) void gemm_proj(const unsigned short* __restrict__ A,
                                                 const unsigned short* __restrict__ W2T,
                                                 const unsigned short* __restrict__ bproj,
                                                 void* __restrict__ outv,
                                                 const int* __restrict__ flag) {
  __shared__ unsigned short As[128 * 32];
  __shared__ unsigned short Bs[128 * 32];
  int m0 = blockIdx.y * 128, n0 = blockIdx.x * 128;
  f32x4 acc[4][4] = {};
  gemm_core(A, W2T, ND, m0, n0, As, Bs, acc);
  int isbf = *flag;
  unsigned short* out16 = (unsigned short*)outv;
  float* out32 = (float*)outv;
  int t = threadIdx.x, lane = t & 63, w = t >> 6, wr = w >> 1, wc = w & 1;
  int coln = lane & 15, rbase = (lane >> 4) * 4;
#pragma unroll
  for (int j = 0; j < 4; ++j) {
    int nn = n0 + 64*wc + 16*j + coln;
    float bias = bf2f(bproj[nn]);
#pragma unroll
    for (int i = 0; i < 4; ++i) {
#pragma unroll
      for (int rr = 0; rr < 4; ++rr) {
        int mm = m0 + 64*wr + 16*i + rbase + rr;
        float v = acc[i][j][rr] + bias;
        if (isbf) out16[(size_t)mm * ND + nn] = f2bf(v);
        else      out32[(size_t)mm * ND + nn] = v;
      }
    }
  }
}

extern "C" void kernel_launch(void* const* d_in, const int* in_sizes, int n_in,
                              void* d_out, int out_size, void* d_ws, size_t ws_size,
                              hipStream_t stream) {
  (void)in_sizes; (void)n_in; (void)out_size; (void)ws_size;
  char* ws = (char*)d_ws;
  unsigned short* W1T = (unsigned short*)(ws);                       // 6,291,456
  unsigned short* W2T = (unsigned short*)(ws + 6291456);             // 2,097,152
  unsigned short* qb  = (unsigned short*)(ws + 8388608);             // 16 MB
  unsigned short* kb  = (unsigned short*)(ws + 25165824);            // 16 MB
  unsigned short* vb  = (unsigned short*)(ws + 41943040);            // 16 MB (B,H,E,S)
  unsigned short* ob  = (unsigned short*)(ws + 58720256);            // 16 MB
  unsigned short* bac = (unsigned short*)(ws + 75497472);            // 8 KB
  unsigned short* bpc = (unsigned short*)(ws + 75505664);            // 8 KB
  int*            flg = (int*)(ws + 75513856);
  unsigned short* wac = qb;   // converted w_attn, dead before qb written
  unsigned short* wpc = kb;   // converted w_proj, dead before kb written
  unsigned short* xc  = ob;   // converted x, dead before ob written

  detect_dtype<<<1, 256, 0, stream>>>((const unsigned*)d_in[0], flg);
  conv_to_bf16<<<2048, 256, 0, stream>>>(d_in[0], xc,  NB*NS*ND, flg);
  conv_to_bf16<<<1024, 256, 0, stream>>>(d_in[1], wac, ND*3*NH*NE, flg);
  conv_to_bf16<<<512,  256, 0, stream>>>(d_in[3], wpc, NH*NE*ND, flg);
  conv_to_bf16<<<12,   256, 0, stream>>>(d_in[2], bac, 3*NH*NE, flg);
  conv_to_bf16<<<4,    256, 0, stream>>>(d_in[4], bpc, ND, flg);

  transpose_k<<<dim3(3072/32, 1024/32), dim3(32, 8), 0, stream>>>(wac, W1T, 1024, 3072);
  transpose_k<<<dim3(1024/32, 1024/32), dim3(32, 8), 0, stream>>>(wpc, W2T, 1024, 1024);
  gemm_qkv<<<dim3(3072/128, NM/128), 256, 0, stream>>>(xc, W1T, bac, qb, kb, vb);
  attn_causal<<<dim3(NS/128, NB*NH), 256, 0, stream>>>(qb, kb, vb, ob);
  gemm_proj<<<dim3(1024/128, NM/128), 256, 0, stream>>>(ob, W2T, bpc, d_out, flg);
}